// Round 11
// baseline (270.394 us; speedup 1.0000x reference)
//
#include <hip/hip_runtime.h>
#include <math.h>

#define SEQ  2048
#define NBH  64            // B*H = 4*16
#define QT_N (SEQ/128)     // 16 q-tiles of 128 rows per (b,h)

typedef __bf16 bf16;
typedef float  f4v   __attribute__((ext_vector_type(4)));
typedef float  f32x4 __attribute__((ext_vector_type(4)));
typedef __bf16 bf16x8 __attribute__((ext_vector_type(8)));
typedef __bf16 bf16x4 __attribute__((ext_vector_type(4)));

typedef unsigned int u32g __attribute__((address_space(1)));
typedef unsigned int u32l __attribute__((address_space(3)));

// async global->LDS, 16B per lane; LDS dest is wave-uniform base + lane*16.
__device__ __forceinline__ void async16(const void* g, void* l) {
    __builtin_amdgcn_global_load_lds((const u32g*)g, (u32l*)l, 16, 0, 0);
}

// ---------------------------------------------------------------------------
// Fused fp32->bf16 cast of x, Wq*(0.125*log2e), Wk, Wv, Wo.
// ---------------------------------------------------------------------------
__global__ __launch_bounds__(256)
void castall(const float* __restrict__ x,  const float* __restrict__ wq,
             const float* __restrict__ wk, const float* __restrict__ wv,
             const float* __restrict__ wo, bf16* __restrict__ dst)
{
    const int i = (blockIdx.x * 256 + threadIdx.x) * 4;
    const float* s; int off; float sc = 1.f;
    if (i < 8388608)       { s = x;  off = 0; }
    else if (i < 9437184)  { s = wq; off = 8388608;  sc = 0.18033688011f; } // 0.125*log2(e)
    else if (i < 10485760) { s = wk; off = 9437184;  }
    else if (i < 11534336) { s = wv; off = 10485760; }
    else                   { s = wo; off = 11534336; }
    f4v v = *(const f4v*)&s[i - off];
    bf16x4 o;
    o[0] = (bf16)(v[0] * sc);
    o[1] = (bf16)(v[1] * sc);
    o[2] = (bf16)(v[2] * sc);
    o[3] = (bf16)(v[3] * sc);
    *(bf16x4*)&dst[i] = o;
}

// ---------------------------------------------------------------------------
// 256x256 deep-phase bf16 GEMM for the QKV projection (MODE0 head-split out).
// BK=64, 8 waves (2M x 4N, per-wave C = 128x64), dynamic LDS 128 KB:
//   buf b: A at elem b*32768 ([256 rows][64 k], 128B rows, XOR-swizzled
//   byte ^= (row&7)<<4), B at b*32768+16384. Double-buffered at K-tile
//   granularity with the r4-verified ledger:
//     tile t: ISSUE 8 stage loads for t+1 into buf^1 (aged 4 phases)
//             4 phases {ds_read frags; barrier; setprio; 16 MFMA; setprio;
//             barrier}; boundary vmcnt(0)+barrier.
//   WAR: buf^1 (tile t-1's data) was last read before the t-1->t boundary
//   barrier, so re-staging it during tile t is safe. Load visibility: each
//   wave waits its own 8 loads (vmcnt(0)), then barrier.
// ---------------------------------------------------------------------------
__global__ __launch_bounds__(512, 2)
void gemm8(const bf16* __restrict__ A, const bf16* __restrict__ Bw,
           bf16* __restrict__ Oq, bf16* __restrict__ Ok, bf16* __restrict__ Ov)
{
    extern __shared__ bf16 lds[];      // 131072 B
    const int t    = threadIdx.x;      // 0..511
    const int lane = t & 63;
    const int w    = t >> 6;           // 0..7
    const int lr   = lane & 15;
    const int lk   = lane >> 4;
    const int m0   = blockIdx.y * 256;
    const int n0   = blockIdx.x * 256;
    const int wr   = (w >> 2) * 128;   // M-half
    const int wc   = (w & 3) * 64;     // N-quarter

    // fragment read offsets: row = (16-mult) + lr  ->  row&7 == lr&7
    const int swz = (lr & 7) << 4;
    const int ko0 = (lk * 16) ^ swz;          // kk=0 byte offset within 128B row
    const int ko1 = (64 + lk * 16) ^ swz;     // kk=1

    // staging map: thread t covers bytes t*16 + j*8192 of each 32KB region
    const int srow0 = t >> 3;                                   // + j*64
    const int soff0 = (((t * 16) & 127) ^ ((srow0 & 7) << 4)) >> 1;  // elems
    const bf16* Ag = A  + (size_t)(m0 + srow0) * 1024 + soff0;
    const bf16* Bg = Bw + (size_t)(n0 + srow0) * 1024 + soff0;

    f32x4 acc[8][4];
    #pragma unroll
    for (int mi = 0; mi < 8; ++mi)
        #pragma unroll
        for (int ni = 0; ni < 4; ++ni) acc[mi][ni] = f32x4{0.f, 0.f, 0.f, 0.f};

    auto STAGE = [&](int kt, int bsel) {
        bf16* Ad = lds + bsel * 32768 + w * 512;
        bf16* Bd = Ad + 16384;
        #pragma unroll
        for (int j = 0; j < 4; ++j)
            async16(Ag + (size_t)j * 65536 + kt * 64, Ad + j * 4096);
        #pragma unroll
        for (int j = 0; j < 4; ++j)
            async16(Bg + (size_t)j * 65536 + kt * 64, Bd + j * 4096);
    };

#define ARD(buf, R, KO) (*(const bf16x8*)((const char*)(buf) + (R) * 128 + (KO)))
#define MFMA_(a, b, c) __builtin_amdgcn_mfma_f32_16x16x32_bf16(a, b, c, 0, 0, 0)

    // prologue: stage tile 0 into buf 0
    STAGE(0, 0);
    asm volatile("s_waitcnt vmcnt(0)" ::: "memory");
    __builtin_amdgcn_s_barrier();

    for (int tt = 0; tt < 16; ++tt) {
        const int cur = tt & 1;
        const bf16* Ab = lds + cur * 32768;
        const bf16* Bb = Ab + 16384;
        if (tt + 1 < 16) STAGE(tt + 1, cur ^ 1);

        bf16x8 av[4][2], blo[2][2], bhi[2][2];
        // ---- phase 0: a(m-lo) + b(n-lo); MFMA Q(lo,lo) ----
        #pragma unroll
        for (int mi = 0; mi < 4; ++mi) {
            int R = wr + mi * 16 + lr;
            av[mi][0] = ARD(Ab, R, ko0);
            av[mi][1] = ARD(Ab, R, ko1);
        }
        #pragma unroll
        for (int ni = 0; ni < 2; ++ni) {
            int R = wc + ni * 16 + lr;
            blo[ni][0] = ARD(Bb, R, ko0);
            blo[ni][1] = ARD(Bb, R, ko1);
        }
        __builtin_amdgcn_s_barrier();
        __builtin_amdgcn_s_setprio(1);
        #pragma unroll
        for (int mi = 0; mi < 4; ++mi)
            #pragma unroll
            for (int ni = 0; ni < 2; ++ni)
                #pragma unroll
                for (int kk = 0; kk < 2; ++kk)
                    acc[mi][ni] = MFMA_(av[mi][kk], blo[ni][kk], acc[mi][ni]);
        __builtin_amdgcn_s_setprio(0);
        __builtin_amdgcn_s_barrier();
        // ---- phase 1: b(n-hi); MFMA Q(lo,hi) ----
        #pragma unroll
        for (int ni = 0; ni < 2; ++ni) {
            int R = wc + (ni + 2) * 16 + lr;
            bhi[ni][0] = ARD(Bb, R, ko0);
            bhi[ni][1] = ARD(Bb, R, ko1);
        }
        __builtin_amdgcn_s_barrier();
        __builtin_amdgcn_s_setprio(1);
        #pragma unroll
        for (int mi = 0; mi < 4; ++mi)
            #pragma unroll
            for (int ni = 0; ni < 2; ++ni)
                #pragma unroll
                for (int kk = 0; kk < 2; ++kk)
                    acc[mi][ni + 2] = MFMA_(av[mi][kk], bhi[ni][kk], acc[mi][ni + 2]);
        __builtin_amdgcn_s_setprio(0);
        __builtin_amdgcn_s_barrier();
        // ---- phase 2: a(m-hi); MFMA Q(hi,hi) ----
        #pragma unroll
        for (int mi = 0; mi < 4; ++mi) {
            int R = wr + (mi + 4) * 16 + lr;
            av[mi][0] = ARD(Ab, R, ko0);
            av[mi][1] = ARD(Ab, R, ko1);
        }
        __builtin_amdgcn_s_barrier();
        __builtin_amdgcn_s_setprio(1);
        #pragma unroll
        for (int mi = 0; mi < 4; ++mi)
            #pragma unroll
            for (int ni = 0; ni < 2; ++ni)
                #pragma unroll
                for (int kk = 0; kk < 2; ++kk)
                    acc[mi + 4][ni + 2] = MFMA_(av[mi][kk], bhi[ni][kk], acc[mi + 4][ni + 2]);
        __builtin_amdgcn_s_setprio(0);
        __builtin_amdgcn_s_barrier();
        // ---- phase 3: MFMA Q(hi,lo) (blo still live); boundary ----
        __builtin_amdgcn_s_setprio(1);
        #pragma unroll
        for (int mi = 0; mi < 4; ++mi)
            #pragma unroll
            for (int ni = 0; ni < 2; ++ni)
                #pragma unroll
                for (int kk = 0; kk < 2; ++kk)
                    acc[mi + 4][ni] = MFMA_(av[mi][kk], blo[ni][kk], acc[mi + 4][ni]);
        __builtin_amdgcn_s_setprio(0);
        if (tt + 1 < 16) asm volatile("s_waitcnt vmcnt(0)" ::: "memory");
        __builtin_amdgcn_s_barrier();
    }

    // epilogue: head-split scatter. C row = lk*4+rr, col = lr within frag.
    #pragma unroll
    for (int mi = 0; mi < 8; ++mi) {
        #pragma unroll
        for (int rr = 0; rr < 4; ++rr) {
            int m  = m0 + wr + mi * 16 + lk * 4 + rr;
            int bb = m >> 11, ss = m & 2047;
            #pragma unroll
            for (int ni = 0; ni < 4; ++ni) {
                int n   = n0 + wc + ni * 16 + lr;
                int mat = n >> 10;
                int o   = n & 1023;
                int hh  = o >> 6, dd = o & 63;
                bf16* dst = (mat == 0) ? Oq : (mat == 1) ? Ok : Ov;
                dst[(((size_t)(bb * 16 + hh)) * SEQ + ss) * 64 + dd] =
                    (bf16)acc[mi][ni][rr];
            }
        }
    }
#undef ARD
#undef MFMA_
}

// ---------------------------------------------------------------------------
// bf16 MFMA GEMM, m97 structure (kept for the output projection).
// MODE 1: N=1024 -> fp32 row-major Of [m][1024]
// ---------------------------------------------------------------------------
template<int MODE>
__global__ __launch_bounds__(256)
void gemm_bf16(const bf16* __restrict__ A, const bf16* __restrict__ Bw,
               bf16* __restrict__ Oq, bf16* __restrict__ Ok, bf16* __restrict__ Ov,
               float* __restrict__ Of)
{
    __shared__ bf16 As[4096];   // [128 rows][32 k] = 8KB
    __shared__ bf16 Bs[4096];

    const int t    = threadIdx.x;
    const int lane = t & 63;
    const int w    = t >> 6;
    const int m0   = blockIdx.y * 128;
    const int n0   = blockIdx.x * 128;
    const int wr   = (w >> 1) * 64;
    const int wc   = (w & 1) * 64;
    const int lr   = lane & 15;
    const int lk   = lane >> 4;

    f32x4 acc[4][4];
    #pragma unroll
    for (int i = 0; i < 4; ++i)
        #pragma unroll
        for (int j = 0; j < 4; ++j) acc[i][j] = f32x4{0.f, 0.f, 0.f, 0.f};

    int rowi[2], srcoff[2];
    #pragma unroll
    for (int it = 0; it < 2; ++it) {
        int b    = t * 16 + it * 4096;
        int row  = b >> 6;          // 64B per row
        int koff = b & 63;
        rowi[it]   = row;
        srcoff[it] = (koff ^ (((row >> 1) & 3) << 4)) >> 1;
    }
    const bf16* Abase = A  + (size_t)m0 * 1024;
    const bf16* Bbase = Bw + (size_t)n0 * 1024;

    for (int k0 = 0; k0 < 1024; k0 += 32) {
        __syncthreads();
        #pragma unroll
        for (int it = 0; it < 2; ++it) {
            async16(Abase + (size_t)rowi[it] * 1024 + k0 + srcoff[it],
                    &As[w * 512 + it * 2048]);
            async16(Bbase + (size_t)rowi[it] * 1024 + k0 + srcoff[it],
                    &Bs[w * 512 + it * 2048]);
        }
        __syncthreads();

        bf16x8 af[4], bfr[4];
        #pragma unroll
        for (int mi = 0; mi < 4; ++mi) {
            int row = wr + mi * 16 + lr;
            af[mi] = *(const bf16x8*)((const char*)As + row * 64 +
                                      ((lk * 16) ^ (((row >> 1) & 3) << 4)));
        }
        #pragma unroll
        for (int ni = 0; ni < 4; ++ni) {
            int row = wc + ni * 16 + lr;
            bfr[ni] = *(const bf16x8*)((const char*)Bs + row * 64 +
                                       ((lk * 16) ^ (((row >> 1) & 3) << 4)));
        }
        #pragma unroll
        for (int mi = 0; mi < 4; ++mi)
            #pragma unroll
            for (int ni = 0; ni < 4; ++ni)
                acc[mi][ni] = __builtin_amdgcn_mfma_f32_16x16x32_bf16(
                    af[mi], bfr[ni], acc[mi][ni], 0, 0, 0);
    }

    #pragma unroll
    for (int mi = 0; mi < 4; ++mi) {
        #pragma unroll
        for (int r = 0; r < 4; ++r) {
            int m = m0 + wr + mi * 16 + lk * 4 + r;
            if (MODE == 0) {
                int bb = m >> 11, ss = m & 2047;
                #pragma unroll
                for (int ni = 0; ni < 4; ++ni) {
                    int n   = n0 + wc + ni * 16 + lr;
                    int mat = n >> 10;
                    int o   = n & 1023;
                    int hh  = o >> 6, dd = o & 63;
                    bf16* dst = (mat == 0) ? Oq : (mat == 1) ? Ok : Ov;
                    dst[(((size_t)(bb * 16 + hh)) * SEQ + ss) * 64 + dd] =
                        (bf16)acc[mi][ni][r];
                }
            } else {
                #pragma unroll
                for (int ni = 0; ni < 4; ++ni) {
                    int n = n0 + wc + ni * 16 + lr;
                    Of[(size_t)m * 1024 + n] = acc[mi][ni][r];
                }
            }
        }
    }
}

// ---------------------------------------------------------------------------
// V [bh][s][64] -> Vt [bh][64][s]   (64x64 LDS tile transpose)
// ---------------------------------------------------------------------------
__global__ __launch_bounds__(256)
void vtrans(const bf16* __restrict__ V, bf16* __restrict__ Vt) {
    __shared__ bf16 ts[64][72];
    const int bh = blockIdx.y;
    const int st = blockIdx.x;
    const int t  = threadIdx.x;
    const int r  = t >> 3;
    const int c8 = (t & 7) * 8;

    #pragma unroll
    for (int it = 0; it < 2; ++it) {
        int row = r + it * 32;
        bf16x8 v = *(const bf16x8*)&V[((size_t)bh * SEQ + st * 64 + row) * 64 + c8];
        #pragma unroll
        for (int j = 0; j < 8; ++j) ts[c8 + j][row] = v[j];
    }
    __syncthreads();
    #pragma unroll
    for (int it = 0; it < 2; ++it) {
        int dk = r + it * 32;
        bf16x8 v = *(const bf16x8*)&ts[dk][c8];
        *(bf16x8*)&Vt[((size_t)bh * 64 + dk) * SEQ + st * 64 + c8] = v;
    }
}

// ---------------------------------------------------------------------------
// MFMA flash attention (verified r7): causal, work-paired, 2-deep pipelined,
// 8 waves x 16 q-rows, static-max exp2 softmax, deferred l-reduce.
// ---------------------------------------------------------------------------
__global__ __launch_bounds__(512)
void fattn(const bf16* __restrict__ Q, const bf16* __restrict__ K,
           const bf16* __restrict__ Vt, bf16* __restrict__ AO)
{
    __shared__ bf16 Ks[2][4096];
    __shared__ bf16 Vs[2][4096];
    __shared__ bf16 Ps[8][1024];

    const int pr   = blockIdx.x;
    const int bh   = blockIdx.y;
    const int t    = threadIdx.x;
    const int lane = t & 63;
    const int w    = t >> 6;
    const int lr   = lane & 15;
    const int lk   = lane >> 4;
    const int b    = bh >> 4, h = bh & 15;

    const int by   = t * 16;
    const int srow = by >> 7;
    const int soff = ((by & 127) ^ ((srow & 7) << 4)) >> 1;

    #pragma unroll 1
    for (int seg = 0; seg < 2; ++seg) {
        const int qt  = seg ? pr : (QT_N - 1 - pr);
        const int q0  = qt * 128 + w * 16;
        const int nkv = 2 * qt + 2;

        bf16x8 qf[2];
        #pragma unroll
        for (int kc = 0; kc < 2; ++kc)
            qf[kc] = *(const bf16x8*)
                &Q[((size_t)bh * SEQ + q0 + lr) * 64 + kc * 32 + lk * 8];

        f32x4 oacc[4];
        float l_[4];
        #pragma unroll
        for (int r = 0; r < 4; ++r) l_[r] = 0.f;
        #pragma unroll
        for (int nd = 0; nd < 4; ++nd) oacc[nd] = f32x4{0.f, 0.f, 0.f, 0.f};

        async16(&K [((size_t)bh * SEQ + srow) * 64 + soff], &Ks[0][w * 512]);
        async16(&Vt[((size_t)bh * 64 + srow) * SEQ + soff], &Vs[0][w * 512]);

        for (int kv = 0; kv < nkv; ++kv) {
            const int cur = kv & 1;
            if (kv + 1 < nkv) {
                const int nxt = cur ^ 1;
                async16(&K [((size_t)bh * SEQ + (kv + 1) * 64 + srow) * 64 + soff],
                        &Ks[nxt][w * 512]);
                async16(&Vt[((size_t)bh * 64 + srow) * SEQ + (kv + 1) * 64 + soff],
                        &Vs[nxt][w * 512]);
                asm volatile("s_waitcnt vmcnt(2)" ::: "memory");
            } else {
                asm volatile("s_waitcnt vmcnt(0)" ::: "memory");
            }
            __builtin_amdgcn_s_barrier();

            if (kv * 64 <= q0 + 15) {
                f32x4 sv[4];
                #pragma unroll
                for (int ni = 0; ni < 4; ++ni) sv[ni] = f32x4{0.f,0.f,0.f,0.f};
                __builtin_amdgcn_s_setprio(1);
                #pragma unroll
                for (int ni = 0; ni < 4; ++ni) {
                    #pragma unroll
                    for (int kc = 0; kc < 2; ++kc) {
                        int krow = ni * 16 + lr;
                        bf16x8 kf = *(const bf16x8*)((const char*)&Ks[cur][0] + krow * 128 +
                                    ((kc * 64 + lk * 16) ^ ((krow & 7) << 4)));
                        sv[ni] = __builtin_amdgcn_mfma_f32_16x16x32_bf16(
                            qf[kc], kf, sv[ni], 0, 0, 0);
                    }
                }
                __builtin_amdgcn_s_setprio(0);
                if (kv * 64 + 63 > q0) {
                    #pragma unroll
                    for (int ni = 0; ni < 4; ++ni)
                        #pragma unroll
                        for (int r = 0; r < 4; ++r) {
                            int qg = q0 + lk * 4 + r;
                            int kp = kv * 64 + ni * 16 + lr;
                            if (kp > qg) sv[ni][r] = -3.0e38f;
                        }
                }
                #pragma unroll
                for (int r = 0; r < 4; ++r) {
                    int   prow  = lk * 4 + r;
                    char* pbase = (char*)&Ps[w][0] + prow * 128;
                    #pragma unroll
                    for (int ni = 0; ni < 4; ++ni) {
                        float p = exp2f(sv[ni][r]);
                        l_[r] += p;
                        int col2 = (ni * 16 + lr) * 2;
                        *(bf16*)(pbase + (col2 ^ ((prow & 7) << 4))) = (bf16)p;
                    }
                }
                __builtin_amdgcn_s_setprio(1);
                #pragma unroll
                for (int kc = 0; kc < 2; ++kc) {
                    bf16x8 pa = *(const bf16x8*)((const char*)&Ps[w][0] + lr * 128 +
                                ((kc * 64 + lk * 16) ^ ((lr & 7) << 4)));
                    #pragma unroll
                    for (int nd = 0; nd < 4; ++nd) {
                        int vrow = nd * 16 + lr;
                        bf16x8 vf = *(const bf16x8*)((const char*)&Vs[cur][0] + vrow * 128 +
                                    ((kc * 64 + lk * 16) ^ ((vrow & 7) << 4)));
                        oacc[nd] = __builtin_amdgcn_mfma_f32_16x16x32_bf16(
                            pa, vf, oacc[nd], 0, 0, 0);
                    }
                }
                __builtin_amdgcn_s_setprio(0);
            }
            __builtin_amdgcn_s_barrier();
        }

        #pragma unroll
        for (int r = 0; r < 4; ++r) {
            #pragma unroll
            for (int off = 1; off < 16; off <<= 1)
                l_[r] += __shfl_xor(l_[r], off);
        }
        #pragma unroll
        for (int r = 0; r < 4; ++r) {
            int   srow2 = q0 + lk * 4 + r;
            float rl    = 1.f / l_[r];
            #pragma unroll
            for (int nd = 0; nd < 4; ++nd) {
                int dk = nd * 16 + lr;
                AO[((size_t)(b * SEQ + srow2)) * 1024 + h * 64 + dk] =
                    (bf16)(oacc[nd][r] * rl);
            }
        }
    }
}

// ---------------------------------------------------------------------------
extern "C" void kernel_launch(void* const* d_in, const int* in_sizes, int n_in,
                              void* d_out, int out_size, void* d_ws, size_t ws_size,
                              hipStream_t stream)
{
    const float* x  = (const float*)d_in[0];
    const float* Wq = (const float*)d_in[1];
    const float* Wk = (const float*)d_in[2];
    const float* Wv = (const float*)d_in[3];
    const float* Wo = (const float*)d_in[4];
    float* out = (float*)d_out;

    const size_t NE = (size_t)8192 * 1024;
    bf16* Xb    = (bf16*)d_ws;               // [8192][1024]
    bf16* Wqkvb = Xb + NE;                   // [3072][1024]  (Wq*scl | Wk | Wv)
    bf16* Wob   = Wqkvb + (size_t)3 * 1024 * 1024;
    bf16* Qb    = Wob   + (size_t)1024 * 1024;   // [64][2048][64]
    bf16* Kb    = Qb  + NE;
    bf16* Vb    = Kb  + NE;
    bf16* Vtb   = Vb  + NE;                  // [64][64][2048]
    bf16* AOb   = Vtb + NE;                  // [8192][1024]

    // allow 128 KB dynamic LDS for gemm8 (host-side attr, idempotent, not
    // a stream op -> graph-capture safe)
    hipFuncSetAttribute(reinterpret_cast<const void*>(&gemm8),
                        hipFuncAttributeMaxDynamicSharedMemorySize, 131072);

    castall<<<12288, 256, 0, stream>>>(x, Wq, Wk, Wv, Wo, Xb);

    gemm8<<<dim3(12, 32), 512, 131072, stream>>>(Xb, Wqkvb, Qb, Kb, Vb);

    vtrans<<<dim3(32, 64), 256, 0, stream>>>(Vb, Vtb);

    fattn<<<dim3(8, NBH), 512, 0, stream>>>(Qb, Kb, Vtb, AOb);

    dim3 g3(8, 64);    // N=1024, M=8192
    gemm_bf16<1><<<g3, 256, 0, stream>>>(AOb, Wob, nullptr, nullptr, nullptr, out);
}